// Round 1
// baseline (131.443 us; speedup 1.0000x reference)
//
#include <hip/hip_runtime.h>
#include <float.h>
#include <math.h>

// Problem constants (from reference)
constexpr int B  = 16;
constexpr int VS = 10475;
constexpr int VO = 8192;
constexpr int K  = 64;
constexpr int PS = 1024;
constexpr int PO = 2048;

constexpr int BLOCK = 256;
constexpr int I_PER_BLOCK = 256;            // queries per block (1 per thread)
constexpr int BLOCKS_PER_K = PS / I_PER_BLOCK;  // 4
constexpr int NBLOCKS = K * BLOCKS_PER_K;       // 256

__global__ __launch_bounds__(BLOCK)
void contact_main(const float* __restrict__ smplx_v,
                  const float* __restrict__ object_v,
                  const int*   __restrict__ smpl_part_idx,
                  const int*   __restrict__ obj_part_idx,
                  const int*   __restrict__ batch_idx,
                  float*       __restrict__ partial)
{
    __shared__ float4 so[PO];      // (ox, oy, oz, 0.5*|o|^2)  -> 32 KiB
    __shared__ float  red[BLOCK];

    const int blk    = blockIdx.x;
    const int k      = blk / BLOCKS_PER_K;
    const int ichunk = blk % BLOCKS_PER_K;
    const int tid    = threadIdx.x;

    const int b = batch_idx[k];
    const float* __restrict__ ov = object_v + (size_t)b * VO * 3;

    // Gather object points for this pair into LDS.
    for (int j = tid; j < PO; j += BLOCK) {
        const int oj = obj_part_idx[k * PO + j];
        const float ox = ov[oj * 3 + 0];
        const float oy = ov[oj * 3 + 1];
        const float oz = ov[oj * 3 + 2];
        so[j] = make_float4(ox, oy, oz, 0.5f * (ox * ox + oy * oy + oz * oz));
    }
    __syncthreads();

    // Each thread owns one query point.
    const int i  = ichunk * I_PER_BLOCK + tid;
    const int si = smpl_part_idx[k * PS + i];
    const float* __restrict__ sv = smplx_v + ((size_t)b * VS + si) * 3;
    const float sx = sv[0], sy = sv[1], sz = sv[2];
    const float nsx = -sx, nsy = -sy, nsz = -sz;
    const float s2 = sx * sx + sy * sy + sz * sz;

    // min over j of (0.5*|o|^2 - s.o);  d^2 = s2 + 2*min_t
    float mint = FLT_MAX;
    #pragma unroll 8
    for (int j = 0; j < PO; ++j) {
        const float4 o = so[j];
        float t = fmaf(o.x, nsx, o.w);
        t = fmaf(o.y, nsy, t);
        t = fmaf(o.z, nsz, t);
        mint = fminf(mint, t);
    }
    const float d2 = fmaxf(s2 + 2.0f * mint, 0.0f);
    const float v  = sqrtf(d2);

    // Deterministic block tree-reduction.
    red[tid] = v;
    __syncthreads();
    for (int s = BLOCK / 2; s > 0; s >>= 1) {
        if (tid < s) red[tid] += red[tid + s];
        __syncthreads();
    }
    if (tid == 0) partial[blk] = red[0];
}

__global__ __launch_bounds__(BLOCK)
void contact_final(const float* __restrict__ partial,
                   float*       __restrict__ out)
{
    __shared__ float red[BLOCK];
    const int tid = threadIdx.x;
    red[tid] = (tid < NBLOCKS) ? partial[tid] : 0.0f;
    __syncthreads();
    for (int s = BLOCK / 2; s > 0; s >>= 1) {
        if (tid < s) red[tid] += red[tid + s];
        __syncthreads();
    }
    if (tid == 0) out[0] = red[0] * (1.0f / (float)(K * PS));
}

extern "C" void kernel_launch(void* const* d_in, const int* in_sizes, int n_in,
                              void* d_out, int out_size, void* d_ws, size_t ws_size,
                              hipStream_t stream)
{
    const float* smplx_v       = (const float*)d_in[0];
    const float* object_v      = (const float*)d_in[1];
    const int*   smpl_part_idx = (const int*)d_in[2];
    const int*   obj_part_idx  = (const int*)d_in[3];
    const int*   batch_idx     = (const int*)d_in[4];

    float* partial = (float*)d_ws;   // NBLOCKS floats
    float* out     = (float*)d_out;

    contact_main<<<NBLOCKS, BLOCK, 0, stream>>>(
        smplx_v, object_v, smpl_part_idx, obj_part_idx, batch_idx, partial);
    contact_final<<<1, BLOCK, 0, stream>>>(partial, out);
}

// Round 2
// 24.777 us; speedup vs baseline: 5.3050x; 5.3050x over previous
//
#include <hip/hip_runtime.h>
#include <float.h>
#include <math.h>

// Problem constants (from reference)
constexpr int B  = 16;
constexpr int VS = 10475;
constexpr int VO = 8192;
constexpr int K  = 64;
constexpr int PS = 1024;
constexpr int PO = 2048;

// Fast-path geometry
constexpr int JC     = 8;           // object-axis chunks per k
constexpr int JCHUNK = PO / JC;     // 256
constexpr int BLOCK  = 256;
constexpr int Q      = PS / BLOCK;  // 4 queries per thread
constexpr int GRID1  = K * JC;      // 512 blocks = 2 per CU

// ---------------- fast path ----------------

__global__ __launch_bounds__(BLOCK)
void cl_pass1(const float* __restrict__ smplx_v,
              const float* __restrict__ object_v,
              const int*   __restrict__ smpl_part_idx,
              const int*   __restrict__ obj_part_idx,
              const int*   __restrict__ batch_idx,
              float*       __restrict__ partial)   // [JC][K][PS] partial min d^2
{
    __shared__ float4 so[JCHUNK];   // (ox,oy,oz, 0.5*|o|^2) -> 4 KiB

    const int blk = blockIdx.x;
    const int k   = blk / JC;
    const int jc  = blk % JC;
    const int tid = threadIdx.x;

    const int b = batch_idx[k];
    const float* __restrict__ ov = object_v + (size_t)b * VO * 3;

    // Gather this block's object chunk into LDS (JCHUNK == BLOCK: 1/thread).
    {
        const int oj = obj_part_idx[k * PO + jc * JCHUNK + tid];
        const float ox = ov[oj * 3 + 0];
        const float oy = ov[oj * 3 + 1];
        const float oz = ov[oj * 3 + 2];
        so[tid] = make_float4(ox, oy, oz, 0.5f * (ox * ox + oy * oy + oz * oz));
    }

    // Load Q query points into registers (overlaps with other waves' gather).
    float nsx[Q], nsy[Q], nsz[Q], s2[Q], mint[Q];
    #pragma unroll
    for (int q = 0; q < Q; ++q) {
        const int i  = tid + q * BLOCK;
        const int si = smpl_part_idx[k * PS + i];
        const float* __restrict__ sv = smplx_v + ((size_t)b * VS + si) * 3;
        const float sx = sv[0], sy = sv[1], sz = sv[2];
        nsx[q] = -sx; nsy[q] = -sy; nsz[q] = -sz;
        s2[q]  = sx * sx + sy * sy + sz * sz;
        mint[q] = FLT_MAX;
    }
    __syncthreads();

    // min over chunk of (0.5*|o|^2 - s.o); each LDS read feeds 16 VALU ops.
    #pragma unroll 4
    for (int j = 0; j < JCHUNK; ++j) {
        const float4 o = so[j];
        #pragma unroll
        for (int q = 0; q < Q; ++q) {
            float t = fmaf(o.x, nsx[q], o.w);
            t = fmaf(o.y, nsy[q], t);
            t = fmaf(o.z, nsz[q], t);
            mint[q] = fminf(mint[q], t);
        }
    }

    // d^2 = s2 + 2*min_t, clamped; coalesced store.
    float* __restrict__ dst = partial + (size_t)jc * (K * PS) + (size_t)k * PS;
    #pragma unroll
    for (int q = 0; q < Q; ++q) {
        dst[tid + q * BLOCK] = fmaxf(fmaf(2.0f, mint[q], s2[q]), 0.0f);
    }
}

__global__ __launch_bounds__(BLOCK)
void cl_pass2(const float* __restrict__ partial,  // [JC][K][PS]
              float*       __restrict__ ksum)     // [K]
{
    __shared__ float red[BLOCK];
    const int k   = blockIdx.x;
    const int tid = threadIdx.x;

    float sum = 0.0f;
    #pragma unroll
    for (int q = 0; q < Q; ++q) {
        const int i = tid + q * BLOCK;
        float m = partial[(size_t)0 * (K * PS) + (size_t)k * PS + i];
        #pragma unroll
        for (int jc = 1; jc < JC; ++jc)
            m = fminf(m, partial[(size_t)jc * (K * PS) + (size_t)k * PS + i]);
        sum += sqrtf(m);
    }

    red[tid] = sum;
    __syncthreads();
    for (int s = BLOCK / 2; s > 0; s >>= 1) {
        if (tid < s) red[tid] += red[tid + s];
        __syncthreads();
    }
    if (tid == 0) ksum[k] = red[0];
}

__global__ __launch_bounds__(64)
void cl_pass3(const float* __restrict__ ksum, float* __restrict__ out)
{
    const int tid = threadIdx.x;
    float v = ksum[tid];   // K == 64 lanes
    #pragma unroll
    for (int off = 32; off > 0; off >>= 1)
        v += __shfl_down(v, off, 64);
    if (tid == 0) out[0] = v * (1.0f / (float)(K * PS));
}

// ---------------- fallback path (small ws) ----------------

constexpr int FB_BLOCKS_PER_K = 4;
constexpr int FB_NBLOCKS = K * FB_BLOCKS_PER_K;

__global__ __launch_bounds__(BLOCK)
void cl_fallback_main(const float* __restrict__ smplx_v,
                      const float* __restrict__ object_v,
                      const int*   __restrict__ smpl_part_idx,
                      const int*   __restrict__ obj_part_idx,
                      const int*   __restrict__ batch_idx,
                      float*       __restrict__ partial)
{
    __shared__ float4 so[PO];
    __shared__ float  red[BLOCK];

    const int blk    = blockIdx.x;
    const int k      = blk / FB_BLOCKS_PER_K;
    const int ichunk = blk % FB_BLOCKS_PER_K;
    const int tid    = threadIdx.x;

    const int b = batch_idx[k];
    const float* __restrict__ ov = object_v + (size_t)b * VO * 3;

    for (int j = tid; j < PO; j += BLOCK) {
        const int oj = obj_part_idx[k * PO + j];
        const float ox = ov[oj * 3 + 0];
        const float oy = ov[oj * 3 + 1];
        const float oz = ov[oj * 3 + 2];
        so[j] = make_float4(ox, oy, oz, 0.5f * (ox * ox + oy * oy + oz * oz));
    }
    __syncthreads();

    const int i  = ichunk * BLOCK + tid;
    const int si = smpl_part_idx[k * PS + i];
    const float* __restrict__ sv = smplx_v + ((size_t)b * VS + si) * 3;
    const float sx = sv[0], sy = sv[1], sz = sv[2];
    const float nsx = -sx, nsy = -sy, nsz = -sz;
    const float s2 = sx * sx + sy * sy + sz * sz;

    float mint = FLT_MAX;
    #pragma unroll 8
    for (int j = 0; j < PO; ++j) {
        const float4 o = so[j];
        float t = fmaf(o.x, nsx, o.w);
        t = fmaf(o.y, nsy, t);
        t = fmaf(o.z, nsz, t);
        mint = fminf(mint, t);
    }
    const float v = sqrtf(fmaxf(s2 + 2.0f * mint, 0.0f));

    red[tid] = v;
    __syncthreads();
    for (int s = BLOCK / 2; s > 0; s >>= 1) {
        if (tid < s) red[tid] += red[tid + s];
        __syncthreads();
    }
    if (tid == 0) partial[blk] = red[0];
}

__global__ __launch_bounds__(BLOCK)
void cl_fallback_final(const float* __restrict__ partial,
                       float*       __restrict__ out)
{
    __shared__ float red[BLOCK];
    const int tid = threadIdx.x;
    red[tid] = (tid < FB_NBLOCKS) ? partial[tid] : 0.0f;
    __syncthreads();
    for (int s = BLOCK / 2; s > 0; s >>= 1) {
        if (tid < s) red[tid] += red[tid + s];
        __syncthreads();
    }
    if (tid == 0) out[0] = red[0] * (1.0f / (float)(K * PS));
}

// ---------------- launcher ----------------

extern "C" void kernel_launch(void* const* d_in, const int* in_sizes, int n_in,
                              void* d_out, int out_size, void* d_ws, size_t ws_size,
                              hipStream_t stream)
{
    const float* smplx_v       = (const float*)d_in[0];
    const float* object_v      = (const float*)d_in[1];
    const int*   smpl_part_idx = (const int*)d_in[2];
    const int*   obj_part_idx  = (const int*)d_in[3];
    const int*   batch_idx     = (const int*)d_in[4];
    float*       out           = (float*)d_out;

    const size_t need = (size_t)(JC * K * PS + K) * sizeof(float); // 2 MiB + 256 B

    if (ws_size >= need) {
        float* partial = (float*)d_ws;              // [JC][K][PS]
        float* ksum    = partial + (size_t)JC * K * PS;  // [K]
        cl_pass1<<<GRID1, BLOCK, 0, stream>>>(
            smplx_v, object_v, smpl_part_idx, obj_part_idx, batch_idx, partial);
        cl_pass2<<<K, BLOCK, 0, stream>>>(partial, ksum);
        cl_pass3<<<1, 64, 0, stream>>>(ksum, out);
    } else {
        float* partial = (float*)d_ws;              // [FB_NBLOCKS]
        cl_fallback_main<<<FB_NBLOCKS, BLOCK, 0, stream>>>(
            smplx_v, object_v, smpl_part_idx, obj_part_idx, batch_idx, partial);
        cl_fallback_final<<<1, BLOCK, 0, stream>>>(partial, out);
    }
}